// Round 1
// baseline (367.961 us; speedup 1.0000x reference)
//
#include <hip/hip_runtime.h>
#include <hip/hip_bf16.h>
#include <hip/hip_fp16.h>

// ---------------------------------------------------------------------------
// FakeQuantLinear (Q4_K_M fake-quant + GEMM): out = x @ fq(W)^T + bias
// x: [M=4096, K=4096] f32, W: [N=4096, K=4096] f32, bias: [N] f32, out f32.
// Plan: (1) cast x -> bf16, (2) fake-quant W -> bf16, (3) m97-style bf16 MFMA
// GEMM (128x128 tile, BK=32, global_load_lds width=16).
// ---------------------------------------------------------------------------

typedef __attribute__((ext_vector_type(8))) short bf16x8;   // 8 bf16 = 4 VGPRs
typedef __attribute__((ext_vector_type(4))) float f32x4;    // MFMA acc

__device__ __forceinline__ unsigned short f2bf(float f) {
  // round-to-nearest-even f32 -> bf16 (inputs are finite)
  unsigned int u = __float_as_uint(f);
  u += 0x7fffu + ((u >> 16) & 1u);
  return (unsigned short)(u >> 16);
}

// ---------------------------------------------------------------------------
// Kernel 1: cast x (f32) -> bf16 bits. 8 elems/thread.
// ---------------------------------------------------------------------------
__global__ __launch_bounds__(256) void cast_x_kernel(
    const float* __restrict__ x, unsigned short* __restrict__ xb) {
  const size_t i = ((size_t)blockIdx.x * 256 + threadIdx.x) * 8;
  const float4 a = *(const float4*)(x + i);
  const float4 b = *(const float4*)(x + i + 4);
  ushort4 o0 = make_ushort4(f2bf(a.x), f2bf(a.y), f2bf(a.z), f2bf(a.w));
  ushort4 o1 = make_ushort4(f2bf(b.x), f2bf(b.y), f2bf(b.z), f2bf(b.w));
  *(ushort4*)(xb + i) = o0;
  *(ushort4*)(xb + i + 4) = o1;
}

// ---------------------------------------------------------------------------
// Kernel 2: Q4_K_M fake-quant of W (forward value = dequant), output bf16.
// One wave per 256-elem superblock; lane holds 4 consecutive elems; 8 lanes
// per 32-elem sub-block. Butterfly shuffles for sub and super reductions.
// Replicates the reference fp op order exactly (rintf = round-half-even).
// ---------------------------------------------------------------------------
__device__ __forceinline__ float dequant1(float e, float sm, float adj, float scale) {
  float t = (e - sm) - adj;                 // == e - sub_min (up to ref's fp order)
  float q = rintf(t / scale);
  q = fminf(fmaxf(q, 0.0f), 15.0f);
  return (q * scale + adj) + sm;
}

__global__ __launch_bounds__(256) void quant_weight_kernel(
    const float* __restrict__ w, unsigned short* __restrict__ wq) {
  const int lane = threadIdx.x & 63;
  const int wv   = threadIdx.x >> 6;
  const size_t base = (((size_t)blockIdx.x * 4 + wv) * 256) + (size_t)lane * 4;
  const float4 v = *(const float4*)(w + base);

  // per-sub (32 elems = 8 lanes) min/max
  float mn = fminf(fminf(v.x, v.y), fminf(v.z, v.w));
  float mx = fmaxf(fmaxf(v.x, v.y), fmaxf(v.z, v.w));
#pragma unroll
  for (int off = 1; off <= 4; off <<= 1) {
    mn = fminf(mn, __shfl_xor(mn, off));
    mx = fmaxf(mx, __shfl_xor(mx, off));
  }
  const float sub_min = fminf(mn, 0.0f);
  const float sub_max = fmaxf(mx, 0.0f);
  const float scale_raw = fmaxf(sub_max - sub_min, 1e-8f) / 15.0f;

  // across the 8 subs of the superblock
  float smn = scale_raw, smx = scale_raw, supermin = sub_min;
#pragma unroll
  for (int off = 8; off <= 32; off <<= 1) {
    smn = fminf(smn, __shfl_xor(smn, off));
    smx = fmaxf(smx, __shfl_xor(smx, off));
    supermin = fminf(supermin, __shfl_xor(supermin, off));
  }
  // 6-bit quantize the scales (match ref op order)
  const float s_range = fmaxf(smx - smn, 1e-8f);
  float s_int = rintf((scale_raw - smn) / s_range * 63.0f);
  s_int = fminf(fmaxf(s_int, 0.0f), 63.0f);
  float scale = s_int / 63.0f * s_range + smn;
  scale = fmaxf(scale, 1e-8f);

  // super-min through f16 (RNE), adj_min per ref
  const float sm  = __half2float(__float2half(supermin));
  const float adj = sub_min - sm;

  ushort4 o;
  o.x = f2bf(dequant1(v.x, sm, adj, scale));
  o.y = f2bf(dequant1(v.y, sm, adj, scale));
  o.z = f2bf(dequant1(v.z, sm, adj, scale));
  o.w = f2bf(dequant1(v.w, sm, adj, scale));
  *(ushort4*)(wq + base) = o;
}

// ---------------------------------------------------------------------------
// Kernel 3: bf16 MFMA GEMM, C[m,n] = sum_k A[m,k]*B[n,k] + bias[n]
// m97 structure: 128x128 block tile, BK=32, 4 waves (2x2), each wave 64x64 =
// 4x4 MFMA 16x16x32 tiles. Staging via global_load_lds width=16 into unpadded
// row-major LDS tiles [128][32] (uniform base + lane*16 ordering).
// ---------------------------------------------------------------------------
#define BM 128
#define BN 128
#define BK 32

__device__ __forceinline__ void async_cp16(void* lds, const void* g) {
  __builtin_amdgcn_global_load_lds(
      (__attribute__((address_space(1))) void*)(void*)g,
      (__attribute__((address_space(3))) void*)lds, 16, 0, 0);
}

__global__ __launch_bounds__(256) void gemm_bt_kernel(
    const unsigned short* __restrict__ A,   // [M][K] bf16 bits
    const unsigned short* __restrict__ B,   // [N][K] bf16 bits (fq weight)
    const float* __restrict__ bias,         // [N]
    float* __restrict__ C,                  // [M][N] f32
    int M, int N, int K) {
  __shared__ unsigned short lds_a[BM * BK];   // 8 KiB, unpadded (load_lds order)
  __shared__ unsigned short lds_b[BN * BK];   // 8 KiB

  const int tid  = threadIdx.x;
  const int lane = tid & 63;
  const int wv   = tid >> 6;
  const int wm   = wv >> 1;          // wave row (0..1)
  const int wn   = wv & 1;           // wave col (0..1)
  const int bx   = blockIdx.x;       // N tile
  const int by   = blockIdx.y;       // M tile

  // staging map: linear load index i -> row i>>2, k-offset (i&3)*8 ; LDS off i*16B
  const int r0   = tid >> 2;           // 0..63
  const int koff = (tid & 3) * 8;      // 0,8,16,24

  const unsigned short* ga0 = A + (size_t)(by * BM + r0)      * K + koff;
  const unsigned short* ga1 = A + (size_t)(by * BM + r0 + 64) * K + koff;
  const unsigned short* gb0 = B + (size_t)(bx * BN + r0)      * K + koff;
  const unsigned short* gb1 = B + (size_t)(bx * BN + r0 + 64) * K + koff;

  unsigned short* la0 = lds_a + tid * 8;           // *8 ushorts = *16 bytes
  unsigned short* la1 = lds_a + (tid + 256) * 8;
  unsigned short* lb0 = lds_b + tid * 8;
  unsigned short* lb1 = lds_b + (tid + 256) * 8;

  f32x4 acc[4][4] = {};

  // MFMA fragment addressing (16x16x32 bf16):
  //   A: m = lane&15, k = (lane>>4)*8 + j   -> 16B contiguous in LDS row
  //   B: n = lane&15, k = (lane>>4)*8 + j   -> same pattern (B is K-major)
  const int arow = wm * 64 + (lane & 15);
  const int brow = wn * 64 + (lane & 15);
  const int kblk = (lane >> 4) * 8;

  for (int k0 = 0; k0 < K; k0 += BK) {
    async_cp16(la0, ga0 + k0);
    async_cp16(la1, ga1 + k0);
    async_cp16(lb0, gb0 + k0);
    async_cp16(lb1, gb1 + k0);
    __syncthreads();   // drains vmcnt -> LDS tiles valid

    bf16x8 af[4], bfr[4];
#pragma unroll
    for (int i = 0; i < 4; ++i)
      af[i] = *(const bf16x8*)(lds_a + (arow + i * 16) * BK + kblk);
#pragma unroll
    for (int j = 0; j < 4; ++j)
      bfr[j] = *(const bf16x8*)(lds_b + (brow + j * 16) * BK + kblk);

#pragma unroll
    for (int i = 0; i < 4; ++i)
#pragma unroll
      for (int j = 0; j < 4; ++j)
        acc[i][j] = __builtin_amdgcn_mfma_f32_16x16x32_bf16(af[i], bfr[j],
                                                            acc[i][j], 0, 0, 0);
    __syncthreads();   // protect LDS before next stage overwrites
  }

  // Epilogue. C/D layout: col = lane&15, row = (lane>>4)*4 + reg   [m89/m91]
  const int rbase = by * BM + wm * 64 + (lane >> 4) * 4;
  const int cbase = bx * BN + wn * 64 + (lane & 15);
#pragma unroll
  for (int j = 0; j < 4; ++j) {
    const int c = cbase + j * 16;
    const float bv = bias[c];
#pragma unroll
    for (int i = 0; i < 4; ++i) {
#pragma unroll
      for (int r = 0; r < 4; ++r) {
        C[(size_t)(rbase + i * 16 + r) * N + c] = acc[i][j][r] + bv;
      }
    }
  }
}

// ---------------------------------------------------------------------------
extern "C" void kernel_launch(void* const* d_in, const int* in_sizes, int n_in,
                              void* d_out, int out_size, void* d_ws, size_t ws_size,
                              hipStream_t stream) {
  const float* x    = (const float*)d_in[0];
  const float* w    = (const float*)d_in[1];
  const float* bias = (const float*)d_in[2];
  float* out = (float*)d_out;

  const long long xn = in_sizes[0];   // M*K = 16,777,216
  const long long wn = in_sizes[1];   // N*K = 16,777,216
  const int N = in_sizes[2];          // 4096
  const int K = (int)(wn / N);        // 4096
  const int M = (int)(xn / K);        // 4096

  // workspace: bf16 x [M*K] then bf16 fq-weight [N*K] (total 64 MiB)
  unsigned short* xb = (unsigned short*)d_ws;
  unsigned short* wb = xb + (size_t)M * K;

  cast_x_kernel<<<(int)(xn / (256 * 8)), 256, 0, stream>>>(x, xb);
  quant_weight_kernel<<<(int)(wn / (256 * 4)), 256, 0, stream>>>(w, wb);
  gemm_bt_kernel<<<dim3(N / BN, M / BM), 256, 0, stream>>>(xb, wb, bias, out,
                                                           M, N, K);
}

// Round 2
// 361.082 us; speedup vs baseline: 1.0191x; 1.0191x over previous
//
#include <hip/hip_runtime.h>
#include <hip/hip_bf16.h>
#include <hip/hip_fp16.h>

// ---------------------------------------------------------------------------
// FakeQuantLinear (Q4_K_M fake-quant + GEMM): out = x @ fq(W)^T + bias
// R2: (a) XOR-swizzled LDS k-chunk slots to break the 8-way read conflicts
//     (BK=32 rows = 64B stride = only 2 bank phases; swizzle spreads reader
//     bank-groups across all 8 -> 2-way, which is free per m136),
//     (b) cast-x and quant-W fused into one launch (no dependency).
// ---------------------------------------------------------------------------

typedef __attribute__((ext_vector_type(8))) short bf16x8;    // 8 bf16 = 4 VGPRs
typedef __attribute__((ext_vector_type(8))) unsigned short ushort8;
typedef __attribute__((ext_vector_type(4))) float f32x4;     // MFMA acc

__device__ __forceinline__ unsigned short f2bf(float f) {
  unsigned int u = __float_as_uint(f);
  u += 0x7fffu + ((u >> 16) & 1u);
  return (unsigned short)(u >> 16);
}

// ---------------------------------------------------------------------------
// Fused prep: blocks [0, castBlocks) cast x -> bf16 (8 elems/thread);
// blocks [castBlocks, ...) fake-quant W -> bf16 (4 elems/thread, 1 wave per
// 256-elem superblock).
// ---------------------------------------------------------------------------
__device__ __forceinline__ float dequant1(float e, float sm, float adj, float scale) {
  float t = (e - sm) - adj;
  float q = rintf(t / scale);
  q = fminf(fmaxf(q, 0.0f), 15.0f);
  return (q * scale + adj) + sm;
}

__global__ __launch_bounds__(256) void prep_kernel(
    const float* __restrict__ x, unsigned short* __restrict__ xb,
    const float* __restrict__ w, unsigned short* __restrict__ wq,
    int castBlocks) {
  if ((int)blockIdx.x < castBlocks) {
    const size_t i = ((size_t)blockIdx.x * 256 + threadIdx.x) * 8;
    const float4 a = *(const float4*)(x + i);
    const float4 b = *(const float4*)(x + i + 4);
    ushort8 o = {f2bf(a.x), f2bf(a.y), f2bf(a.z), f2bf(a.w),
                 f2bf(b.x), f2bf(b.y), f2bf(b.z), f2bf(b.w)};
    *(ushort8*)(xb + i) = o;
    return;
  }
  const int qb   = blockIdx.x - castBlocks;
  const int lane = threadIdx.x & 63;
  const int wv   = threadIdx.x >> 6;
  const size_t base = (((size_t)qb * 4 + wv) * 256) + (size_t)lane * 4;
  const float4 v = *(const float4*)(w + base);

  // per-sub (32 elems = 8 lanes) min/max
  float mn = fminf(fminf(v.x, v.y), fminf(v.z, v.w));
  float mx = fmaxf(fmaxf(v.x, v.y), fmaxf(v.z, v.w));
#pragma unroll
  for (int off = 1; off <= 4; off <<= 1) {
    mn = fminf(mn, __shfl_xor(mn, off));
    mx = fmaxf(mx, __shfl_xor(mx, off));
  }
  const float sub_min = fminf(mn, 0.0f);
  const float sub_max = fmaxf(mx, 0.0f);
  const float scale_raw = fmaxf(sub_max - sub_min, 1e-8f) / 15.0f;

  // across the 8 subs of the superblock
  float smn = scale_raw, smx = scale_raw, supermin = sub_min;
#pragma unroll
  for (int off = 8; off <= 32; off <<= 1) {
    smn = fminf(smn, __shfl_xor(smn, off));
    smx = fmaxf(smx, __shfl_xor(smx, off));
    supermin = fminf(supermin, __shfl_xor(supermin, off));
  }
  const float s_range = fmaxf(smx - smn, 1e-8f);
  float s_int = rintf((scale_raw - smn) / s_range * 63.0f);
  s_int = fminf(fmaxf(s_int, 0.0f), 63.0f);
  float scale = s_int / 63.0f * s_range + smn;
  scale = fmaxf(scale, 1e-8f);

  const float sm  = __half2float(__float2half(supermin));
  const float adj = sub_min - sm;

  ushort4 o;
  o.x = f2bf(dequant1(v.x, sm, adj, scale));
  o.y = f2bf(dequant1(v.y, sm, adj, scale));
  o.z = f2bf(dequant1(v.z, sm, adj, scale));
  o.w = f2bf(dequant1(v.w, sm, adj, scale));
  *(ushort4*)(wq + base) = o;
}

// ---------------------------------------------------------------------------
// bf16 MFMA GEMM, C[m,n] = sum_k A[m,k]*B[n,k] + bias[n]
// 128x128 tile, BK=32, 4 waves (2x2), each wave 64x64 = 4x4 16x16x32 MFMA.
// LDS k-chunk swizzle: slot c of row r holds global chunk c ^ ((r>>1)&3).
// ---------------------------------------------------------------------------
#define BM 128
#define BN 128
#define BK 32

__device__ __forceinline__ void async_cp16(void* lds, const void* g) {
  __builtin_amdgcn_global_load_lds(
      (__attribute__((address_space(1))) void*)(void*)g,
      (__attribute__((address_space(3))) void*)lds, 16, 0, 0);
}

__global__ __launch_bounds__(256) void gemm_bt_kernel(
    const unsigned short* __restrict__ A,   // [M][K] bf16 bits
    const unsigned short* __restrict__ B,   // [N][K] bf16 bits (fq weight)
    const float* __restrict__ bias,         // [N]
    float* __restrict__ C,                  // [M][N] f32
    int M, int N, int K) {
  __shared__ unsigned short lds_a[BM * BK];   // 8 KiB, unpadded
  __shared__ unsigned short lds_b[BN * BK];   // 8 KiB

  const int tid  = threadIdx.x;
  const int lane = tid & 63;
  const int wv   = tid >> 6;
  const int wm   = wv >> 1;
  const int wn   = wv & 1;
  const int bx   = blockIdx.x;
  const int by   = blockIdx.y;

  // staging map: lane tid -> LDS slot (row=tid>>2, slot=tid&3) at tid*16B.
  // Fetch global chunk (slot ^ ((row>>1)&3)) so slot c of row r holds global
  // chunk c ^ ((r>>1)&3)  [XOR swizzle for reader bank spread].
  const int r0   = tid >> 2;                              // 0..63
  const int cw   = (tid & 3) ^ ((tid >> 3) & 3);          // swizzled chunk
  const int koff = cw * 8;                                // ushort offset

  const unsigned short* ga0 = A + (size_t)(by * BM + r0)      * K + koff;
  const unsigned short* ga1 = A + (size_t)(by * BM + r0 + 64) * K + koff;
  const unsigned short* gb0 = B + (size_t)(bx * BN + r0)      * K + koff;
  const unsigned short* gb1 = B + (size_t)(bx * BN + r0 + 64) * K + koff;

  unsigned short* la0 = lds_a + tid * 8;
  unsigned short* la1 = lds_a + (tid + 256) * 8;
  unsigned short* lb0 = lds_b + tid * 8;
  unsigned short* lb1 = lds_b + (tid + 256) * 8;

  f32x4 acc[4][4] = {};

  // Fragment reads: want k-chunk q = lane>>4 of row r; it lives in slot
  // q ^ ((r>>1)&3). For r = (wave base) + (lane&15) + i*16 the swizzle term
  // reduces to (lane>>1)&3 (i*16 and wave base don't touch bits 1..2).
  const int arow  = wm * 64 + (lane & 15);
  const int brow  = wn * 64 + (lane & 15);
  const int kslot = (((lane >> 4) ^ ((lane >> 1) & 3))) * 8;

  for (int k0 = 0; k0 < K; k0 += BK) {
    async_cp16(la0, ga0 + k0);
    async_cp16(la1, ga1 + k0);
    async_cp16(lb0, gb0 + k0);
    async_cp16(lb1, gb1 + k0);
    __syncthreads();

    bf16x8 af[4], bfr[4];
#pragma unroll
    for (int i = 0; i < 4; ++i)
      af[i] = *(const bf16x8*)(lds_a + (arow + i * 16) * BK + kslot);
#pragma unroll
    for (int j = 0; j < 4; ++j)
      bfr[j] = *(const bf16x8*)(lds_b + (brow + j * 16) * BK + kslot);

#pragma unroll
    for (int i = 0; i < 4; ++i)
#pragma unroll
      for (int j = 0; j < 4; ++j)
        acc[i][j] = __builtin_amdgcn_mfma_f32_16x16x32_bf16(af[i], bfr[j],
                                                            acc[i][j], 0, 0, 0);
    __syncthreads();
  }

  // Epilogue. C/D layout: col = lane&15, row = (lane>>4)*4 + reg
  const int rbase = by * BM + wm * 64 + (lane >> 4) * 4;
  const int cbase = bx * BN + wn * 64 + (lane & 15);
#pragma unroll
  for (int j = 0; j < 4; ++j) {
    const int c = cbase + j * 16;
    const float bv = bias[c];
#pragma unroll
    for (int i = 0; i < 4; ++i) {
#pragma unroll
      for (int r = 0; r < 4; ++r) {
        C[(size_t)(rbase + i * 16 + r) * N + c] = acc[i][j][r] + bv;
      }
    }
  }
}

// ---------------------------------------------------------------------------
extern "C" void kernel_launch(void* const* d_in, const int* in_sizes, int n_in,
                              void* d_out, int out_size, void* d_ws, size_t ws_size,
                              hipStream_t stream) {
  const float* x    = (const float*)d_in[0];
  const float* w    = (const float*)d_in[1];
  const float* bias = (const float*)d_in[2];
  float* out = (float*)d_out;

  const long long xn = in_sizes[0];   // M*K
  const long long wn = in_sizes[1];   // N*K
  const int N = in_sizes[2];
  const int K = (int)(wn / N);
  const int M = (int)(xn / K);

  unsigned short* xb = (unsigned short*)d_ws;
  unsigned short* wb = xb + (size_t)M * K;

  const int castBlocks  = (int)(xn / (256 * 8));
  const int quantBlocks = (int)(wn / (256 * 4));
  prep_kernel<<<castBlocks + quantBlocks, 256, 0, stream>>>(x, xb, w, wb,
                                                            castBlocks);
  gemm_bt_kernel<<<dim3(N / BN, M / BM), 256, 0, stream>>>(xb, wb, bias, out,
                                                           M, N, K);
}

// Round 3
// 319.150 us; speedup vs baseline: 1.1529x; 1.1314x over previous
//
#include <hip/hip_runtime.h>
#include <hip/hip_bf16.h>
#include <hip/hip_fp16.h>

// ---------------------------------------------------------------------------
// FakeQuantLinear (Q4_K_M fake-quant + GEMM): out = x @ fq(W)^T + bias
// R3: (a) GEMM: 256x128 block tile, wave tile 128x64 (8x4 MFMA 16x16x32),
//     32 MFMA per barrier-pair vs 16 -> halved per-MFMA overhead; same
//     proven zero-conflict XOR LDS swizzle. __launch_bounds__(256,2).
//     (b) prep: 16 elems/lane quant (4x fewer shuffles/div per element),
//     reciprocal-multiply dequant.
// ---------------------------------------------------------------------------

typedef __attribute__((ext_vector_type(8))) short bf16x8;    // 8 bf16 = 4 VGPRs
typedef __attribute__((ext_vector_type(8))) unsigned short ushort8;
typedef __attribute__((ext_vector_type(4))) float f32x4;     // MFMA acc

__device__ __forceinline__ unsigned short f2bf(float f) {
  unsigned int u = __float_as_uint(f);
  u += 0x7fffu + ((u >> 16) & 1u);
  return (unsigned short)(u >> 16);
}

// ---------------------------------------------------------------------------
// Fused prep kernel.
// Blocks [0, castBlocks): cast x -> bf16, 8 elems/thread (memory-bound).
// Blocks [castBlocks, ..): Q4_K_M fake-quant of W -> bf16, 16 elems/lane,
//   one 16-lane cluster per 256-elem superblock (4 superblocks/wave).
// ---------------------------------------------------------------------------
__global__ __launch_bounds__(256) void prep_kernel(
    const float* __restrict__ x, unsigned short* __restrict__ xb,
    const float* __restrict__ w, unsigned short* __restrict__ wq,
    int castBlocks) {
  if ((int)blockIdx.x < castBlocks) {
    const size_t i = ((size_t)blockIdx.x * 256 + threadIdx.x) * 8;
    const float4 a = *(const float4*)(x + i);
    const float4 b = *(const float4*)(x + i + 4);
    ushort8 o = {f2bf(a.x), f2bf(a.y), f2bf(a.z), f2bf(a.w),
                 f2bf(b.x), f2bf(b.y), f2bf(b.z), f2bf(b.w)};
    *(ushort8*)(xb + i) = o;
    return;
  }
  const int qb   = blockIdx.x - castBlocks;
  const int lane = threadIdx.x & 63;
  const int wv   = threadIdx.x >> 6;
  const int cl   = lane >> 4;     // cluster (superblock within wave), 0..3
  const int q    = lane & 15;     // lane within cluster; 2 lanes = 1 sub-block
  const size_t base =
      (size_t)qb * 4096 + (size_t)wv * 1024 + (size_t)cl * 256 + (size_t)q * 16;

  const float4 v0 = *(const float4*)(w + base);
  const float4 v1 = *(const float4*)(w + base + 4);
  const float4 v2 = *(const float4*)(w + base + 8);
  const float4 v3 = *(const float4*)(w + base + 12);

  // 16-elem per-lane min/max
  float mn = fminf(fminf(fminf(v0.x, v0.y), fminf(v0.z, v0.w)),
                   fminf(fminf(v1.x, v1.y), fminf(v1.z, v1.w)));
  mn = fminf(mn, fminf(fminf(fminf(v2.x, v2.y), fminf(v2.z, v2.w)),
                       fminf(fminf(v3.x, v3.y), fminf(v3.z, v3.w))));
  float mx = fmaxf(fmaxf(fmaxf(v0.x, v0.y), fmaxf(v0.z, v0.w)),
                   fmaxf(fmaxf(v1.x, v1.y), fmaxf(v1.z, v1.w)));
  mx = fmaxf(mx, fmaxf(fmaxf(fmaxf(v2.x, v2.y), fmaxf(v2.z, v2.w)),
                       fmaxf(fmaxf(v3.x, v3.y), fmaxf(v3.z, v3.w))));

  // sub-block (32 elems = lane pair)
  mn = fminf(mn, __shfl_xor(mn, 1));
  mx = fmaxf(mx, __shfl_xor(mx, 1));
  const float sub_min = fminf(mn, 0.0f);
  const float sub_max = fmaxf(mx, 0.0f);
  const float scale_raw = fmaxf(sub_max - sub_min, 1e-8f) / 15.0f;

  // superblock (8 subs = 16-lane cluster)
  float smn = scale_raw, smx = scale_raw, supermin = sub_min;
#pragma unroll
  for (int off = 2; off <= 8; off <<= 1) {
    smn = fminf(smn, __shfl_xor(smn, off));
    smx = fmaxf(smx, __shfl_xor(smx, off));
    supermin = fminf(supermin, __shfl_xor(supermin, off));
  }
  // 6-bit quantize scales (exact ref op order for the scale itself)
  const float s_range = fmaxf(smx - smn, 1e-8f);
  float s_int = rintf((scale_raw - smn) / s_range * 63.0f);
  s_int = fminf(fmaxf(s_int, 0.0f), 63.0f);
  float scale = s_int / 63.0f * s_range + smn;
  scale = fmaxf(scale, 1e-8f);
  const float inv_scale = 1.0f / scale;   // reciprocal-mul dequant (see R3 note)

  const float sm  = __half2float(__float2half(supermin));
  const float adj = sub_min - sm;

  float e[16] = {v0.x, v0.y, v0.z, v0.w, v1.x, v1.y, v1.z, v1.w,
                 v2.x, v2.y, v2.z, v2.w, v3.x, v3.y, v3.z, v3.w};
  unsigned short o[16];
#pragma unroll
  for (int k = 0; k < 16; ++k) {
    const float t = (e[k] - sm) - adj;
    float qv = rintf(t * inv_scale);
    qv = fminf(fmaxf(qv, 0.0f), 15.0f);
    o[k] = f2bf((qv * scale + adj) + sm);
  }
  *(ushort8*)(wq + base)     = *(ushort8*)(o);
  *(ushort8*)(wq + base + 8) = *(ushort8*)(o + 8);
}

// ---------------------------------------------------------------------------
// bf16 MFMA GEMM, C[m,n] = sum_k A[m,k]*B[n,k] + bias[n]
// Block tile 256x128, BK=32; 4 waves (2x2); wave tile 128x64 = 8x4 MFMA
// 16x16x32. LDS k-chunk XOR swizzle (slot c of row r holds chunk c^((r>>1)&3))
// -> zero bank conflicts (verified R2).
// ---------------------------------------------------------------------------
#define BM 256
#define BN 128
#define BK 32

__device__ __forceinline__ void async_cp16(void* lds, const void* g) {
  __builtin_amdgcn_global_load_lds(
      (__attribute__((address_space(1))) void*)(void*)g,
      (__attribute__((address_space(3))) void*)lds, 16, 0, 0);
}

__global__ __launch_bounds__(256, 2) void gemm_bt_kernel(
    const unsigned short* __restrict__ A,   // [M][K] bf16 bits
    const unsigned short* __restrict__ B,   // [N][K] bf16 bits (fq weight)
    const float* __restrict__ bias,         // [N]
    float* __restrict__ C,                  // [M][N] f32
    int M, int N, int K) {
  __shared__ unsigned short lds_a[BM * BK];   // 16 KiB
  __shared__ unsigned short lds_b[BN * BK];   // 8 KiB

  const int tid  = threadIdx.x;
  const int lane = tid & 63;
  const int wv   = tid >> 6;
  const int wm   = wv >> 1;          // 0..1 -> wave row (128 rows each)
  const int wn   = wv & 1;           // 0..1 -> wave col (64 cols each)
  const int bx   = blockIdx.x;       // N tile (128)
  const int by   = blockIdx.y;       // M tile (256)

  // staging: thread t -> row t>>2 (+64k), slot t&3; fetch chunk (t&3)^((t>>3)&3)
  const int r0   = tid >> 2;
  const int cw   = (tid & 3) ^ ((tid >> 3) & 3);
  const int koff = cw * 8;

  const unsigned short* ga0 = A + (size_t)(by * BM + r0)       * K + koff;
  const unsigned short* ga1 = A + (size_t)(by * BM + r0 + 64)  * K + koff;
  const unsigned short* ga2 = A + (size_t)(by * BM + r0 + 128) * K + koff;
  const unsigned short* ga3 = A + (size_t)(by * BM + r0 + 192) * K + koff;
  const unsigned short* gb0 = B + (size_t)(bx * BN + r0)       * K + koff;
  const unsigned short* gb1 = B + (size_t)(bx * BN + r0 + 64)  * K + koff;

  unsigned short* la0 = lds_a + tid * 8;
  unsigned short* la1 = lds_a + (tid + 256) * 8;
  unsigned short* la2 = lds_a + (tid + 512) * 8;
  unsigned short* la3 = lds_a + (tid + 768) * 8;
  unsigned short* lb0 = lds_b + tid * 8;
  unsigned short* lb1 = lds_b + (tid + 256) * 8;

  f32x4 acc[8][4] = {};

  // fragment addressing: A m=lane&15, k=(lane>>4)*8+j ; swizzled k slot
  const int arow  = wm * 128 + (lane & 15);
  const int brow  = wn * 64 + (lane & 15);
  const int kslot = (((lane >> 4) ^ ((lane >> 1) & 3))) * 8;

  for (int k0 = 0; k0 < K; k0 += BK) {
    async_cp16(la0, ga0 + k0);
    async_cp16(la1, ga1 + k0);
    async_cp16(la2, ga2 + k0);
    async_cp16(la3, ga3 + k0);
    async_cp16(lb0, gb0 + k0);
    async_cp16(lb1, gb1 + k0);
    __syncthreads();

    bf16x8 af[8], bfr[4];
#pragma unroll
    for (int i = 0; i < 8; ++i)
      af[i] = *(const bf16x8*)(lds_a + (arow + i * 16) * BK + kslot);
#pragma unroll
    for (int j = 0; j < 4; ++j)
      bfr[j] = *(const bf16x8*)(lds_b + (brow + j * 16) * BK + kslot);

#pragma unroll
    for (int i = 0; i < 8; ++i)
#pragma unroll
      for (int j = 0; j < 4; ++j)
        acc[i][j] = __builtin_amdgcn_mfma_f32_16x16x32_bf16(af[i], bfr[j],
                                                            acc[i][j], 0, 0, 0);
    __syncthreads();
  }

  // Epilogue. C/D layout: col = lane&15, row = (lane>>4)*4 + reg
  const int rbase = by * BM + wm * 128 + (lane >> 4) * 4;
  const int cbase = bx * BN + wn * 64 + (lane & 15);
#pragma unroll
  for (int j = 0; j < 4; ++j) {
    const int c = cbase + j * 16;
    const float bv = bias[c];
#pragma unroll
    for (int i = 0; i < 8; ++i) {
#pragma unroll
      for (int r = 0; r < 4; ++r) {
        C[(size_t)(rbase + i * 16 + r) * N + c] = acc[i][j][r] + bv;
      }
    }
  }
}

// ---------------------------------------------------------------------------
extern "C" void kernel_launch(void* const* d_in, const int* in_sizes, int n_in,
                              void* d_out, int out_size, void* d_ws, size_t ws_size,
                              hipStream_t stream) {
  const float* x    = (const float*)d_in[0];
  const float* w    = (const float*)d_in[1];
  const float* bias = (const float*)d_in[2];
  float* out = (float*)d_out;

  const long long xn = in_sizes[0];   // M*K
  const long long wn = in_sizes[1];   // N*K
  const int N = in_sizes[2];
  const int K = (int)(wn / N);
  const int M = (int)(xn / K);

  unsigned short* xb = (unsigned short*)d_ws;
  unsigned short* wb = xb + (size_t)M * K;

  const int castBlocks  = (int)(xn / (256 * 8));    // 8 elems/thread
  const int quantBlocks = (int)(wn / 4096);         // 4096 elems/block
  prep_kernel<<<castBlocks + quantBlocks, 256, 0, stream>>>(x, xb, w, wb,
                                                            castBlocks);
  gemm_bt_kernel<<<dim3(N / BN, M / BM), 256, 0, stream>>>(xb, wb, bias, out,
                                                           M, N, K);
}

// Round 4
// 310.420 us; speedup vs baseline: 1.1854x; 1.0281x over previous
//
#include <hip/hip_runtime.h>
#include <hip/hip_bf16.h>
#include <hip/hip_fp16.h>

// ---------------------------------------------------------------------------
// FakeQuantLinear (Q4_K_M fake-quant + GEMM): out = x @ fq(W)^T + bias
// R4: (a) GEMM: double-buffered LDS, ONE barrier/iter, prefetch issued
//     right after the barrier (distance-1) so load latency overlaps the
//     32-MFMA compute phase instead of sitting on the critical path.
//     (b) prep: back to fully-coalesced 4-elem/lane quant (R2 layout) with
//     reciprocal-mul dequant (no IEEE div).
// ---------------------------------------------------------------------------

typedef __attribute__((ext_vector_type(8))) short bf16x8;    // 8 bf16 = 4 VGPRs
typedef __attribute__((ext_vector_type(8))) unsigned short ushort8;
typedef __attribute__((ext_vector_type(4))) float f32x4;     // MFMA acc

__device__ __forceinline__ unsigned short f2bf(float f) {
  unsigned int u = __float_as_uint(f);
  u += 0x7fffu + ((u >> 16) & 1u);
  return (unsigned short)(u >> 16);
}

// ---------------------------------------------------------------------------
// Fused prep kernel.
// Blocks [0, castBlocks): cast x -> bf16, 8 elems/thread.
// Blocks [castBlocks, ..): Q4_K_M fake-quant W -> bf16, 4 elems/lane,
//   1 wave per 256-elem superblock (coalesced: lane stride 16 B).
// ---------------------------------------------------------------------------
__global__ __launch_bounds__(256) void prep_kernel(
    const float* __restrict__ x, unsigned short* __restrict__ xb,
    const float* __restrict__ w, unsigned short* __restrict__ wq,
    int castBlocks) {
  if ((int)blockIdx.x < castBlocks) {
    const size_t i = ((size_t)blockIdx.x * 256 + threadIdx.x) * 8;
    const float4 a = *(const float4*)(x + i);
    const float4 b = *(const float4*)(x + i + 4);
    ushort8 o = {f2bf(a.x), f2bf(a.y), f2bf(a.z), f2bf(a.w),
                 f2bf(b.x), f2bf(b.y), f2bf(b.z), f2bf(b.w)};
    *(ushort8*)(xb + i) = o;
    return;
  }
  const int qb   = blockIdx.x - castBlocks;
  const int lane = threadIdx.x & 63;
  const int wv   = threadIdx.x >> 6;
  const size_t base = (((size_t)qb * 4 + wv) * 256) + (size_t)lane * 4;
  const float4 v = *(const float4*)(w + base);

  // per-sub (32 elems = 8 lanes) min/max
  float mn = fminf(fminf(v.x, v.y), fminf(v.z, v.w));
  float mx = fmaxf(fmaxf(v.x, v.y), fmaxf(v.z, v.w));
#pragma unroll
  for (int off = 1; off <= 4; off <<= 1) {
    mn = fminf(mn, __shfl_xor(mn, off));
    mx = fmaxf(mx, __shfl_xor(mx, off));
  }
  const float sub_min = fminf(mn, 0.0f);
  const float sub_max = fmaxf(mx, 0.0f);
  const float scale_raw = fmaxf(sub_max - sub_min, 1e-8f) / 15.0f;

  // superblock (8 subs)
  float smn = scale_raw, smx = scale_raw, supermin = sub_min;
#pragma unroll
  for (int off = 8; off <= 32; off <<= 1) {
    smn = fminf(smn, __shfl_xor(smn, off));
    smx = fmaxf(smx, __shfl_xor(smx, off));
    supermin = fminf(supermin, __shfl_xor(supermin, off));
  }
  const float s_range = fmaxf(smx - smn, 1e-8f);
  float s_int = rintf((scale_raw - smn) / s_range * 63.0f);
  s_int = fminf(fmaxf(s_int, 0.0f), 63.0f);
  float scale = s_int / 63.0f * s_range + smn;
  scale = fmaxf(scale, 1e-8f);
  const float inv_scale = 1.0f / scale;

  const float sm  = __half2float(__float2half(supermin));
  const float adj = sub_min - sm;

  float e[4] = {v.x, v.y, v.z, v.w};
  ushort4 o;
  unsigned short* op = (unsigned short*)&o;
#pragma unroll
  for (int k = 0; k < 4; ++k) {
    const float t = (e[k] - sm) - adj;
    float qv = rintf(t * inv_scale);
    qv = fminf(fmaxf(qv, 0.0f), 15.0f);
    op[k] = f2bf((qv * scale + adj) + sm);
  }
  *(ushort4*)(wq + base) = o;
}

// ---------------------------------------------------------------------------
// bf16 MFMA GEMM, C[m,n] = sum_k A[m,k]*B[n,k] + bias[n]
// Block tile 256x128, BK=32; 4 waves (2x2); wave tile 128x64 = 8x4 MFMA
// 16x16x32. Double-buffered LDS, one barrier per K-iter, prefetch distance 1.
// LDS k-chunk XOR swizzle (slot c of row r holds chunk c^((r>>1)&3)) ->
// zero bank conflicts (verified R2/R3).
// ---------------------------------------------------------------------------
#define BM 256
#define BN 128
#define BK 32

__device__ __forceinline__ void async_cp16(void* lds, const void* g) {
  __builtin_amdgcn_global_load_lds(
      (__attribute__((address_space(1))) void*)(void*)g,
      (__attribute__((address_space(3))) void*)lds, 16, 0, 0);
}

__global__ __launch_bounds__(256, 2) void gemm_bt_kernel(
    const unsigned short* __restrict__ A,   // [M][K] bf16 bits
    const unsigned short* __restrict__ B,   // [N][K] bf16 bits (fq weight)
    const float* __restrict__ bias,         // [N]
    float* __restrict__ C,                  // [M][N] f32
    int M, int N, int K) {
  __shared__ unsigned short lds_a[2][BM * BK];   // 2 x 16 KiB
  __shared__ unsigned short lds_b[2][BN * BK];   // 2 x 8 KiB

  const int tid  = threadIdx.x;
  const int lane = tid & 63;
  const int wv   = tid >> 6;
  const int wm   = wv >> 1;          // wave row (128 rows each)
  const int wn   = wv & 1;           // wave col (64 cols each)
  const int bx   = blockIdx.x;       // N tile (128)
  const int by   = blockIdx.y;       // M tile (256)

  // staging: thread t -> row t>>2 (+64k), slot t&3; fetch chunk (t&3)^((t>>3)&3)
  const int r0   = tid >> 2;
  const int cw   = (tid & 3) ^ ((tid >> 3) & 3);
  const int koff = cw * 8;

  const unsigned short* ga0 = A + (size_t)(by * BM + r0)       * K + koff;
  const unsigned short* ga1 = A + (size_t)(by * BM + r0 + 64)  * K + koff;
  const unsigned short* ga2 = A + (size_t)(by * BM + r0 + 128) * K + koff;
  const unsigned short* ga3 = A + (size_t)(by * BM + r0 + 192) * K + koff;
  const unsigned short* gb0 = B + (size_t)(bx * BN + r0)       * K + koff;
  const unsigned short* gb1 = B + (size_t)(bx * BN + r0 + 64)  * K + koff;

  const int lo0 = tid * 8, lo1 = (tid + 256) * 8,
            lo2 = (tid + 512) * 8, lo3 = (tid + 768) * 8;

  f32x4 acc[8][4] = {};

  // fragment addressing: A m=lane&15, k=(lane>>4)*8+j ; swizzled k slot
  const int arow  = wm * 128 + (lane & 15);
  const int brow  = wn * 64 + (lane & 15);
  const int kslot = (((lane >> 4) ^ ((lane >> 1) & 3))) * 8;

  // prefetch tile 0 into buffer 0
  async_cp16(lds_a[0] + lo0, ga0);
  async_cp16(lds_a[0] + lo1, ga1);
  async_cp16(lds_a[0] + lo2, ga2);
  async_cp16(lds_a[0] + lo3, ga3);
  async_cp16(lds_b[0] + lo0, gb0);
  async_cp16(lds_b[0] + lo1, gb1);

  for (int k0 = 0; k0 < K; k0 += BK) {
    const int cur = (k0 >> 5) & 1;
    __syncthreads();   // drains prefetch for buf[cur]; ends others' use of buf[cur^1]
    if (k0 + BK < K) {
      const int nxt = cur ^ 1;
      const int kn  = k0 + BK;
      async_cp16(lds_a[nxt] + lo0, ga0 + kn);
      async_cp16(lds_a[nxt] + lo1, ga1 + kn);
      async_cp16(lds_a[nxt] + lo2, ga2 + kn);
      async_cp16(lds_a[nxt] + lo3, ga3 + kn);
      async_cp16(lds_b[nxt] + lo0, gb0 + kn);
      async_cp16(lds_b[nxt] + lo1, gb1 + kn);
    }

    bf16x8 af[8], bfr[4];
#pragma unroll
    for (int i = 0; i < 8; ++i)
      af[i] = *(const bf16x8*)(lds_a[cur] + (arow + i * 16) * BK + kslot);
#pragma unroll
    for (int j = 0; j < 4; ++j)
      bfr[j] = *(const bf16x8*)(lds_b[cur] + (brow + j * 16) * BK + kslot);

#pragma unroll
    for (int i = 0; i < 8; ++i)
#pragma unroll
      for (int j = 0; j < 4; ++j)
        acc[i][j] = __builtin_amdgcn_mfma_f32_16x16x32_bf16(af[i], bfr[j],
                                                            acc[i][j], 0, 0, 0);
  }

  // Epilogue. C/D layout: col = lane&15, row = (lane>>4)*4 + reg
  const int rbase = by * BM + wm * 128 + (lane >> 4) * 4;
  const int cbase = bx * BN + wn * 64 + (lane & 15);
#pragma unroll
  for (int j = 0; j < 4; ++j) {
    const int c = cbase + j * 16;
    const float bv = bias[c];
#pragma unroll
    for (int i = 0; i < 8; ++i) {
#pragma unroll
      for (int r = 0; r < 4; ++r) {
        C[(size_t)(rbase + i * 16 + r) * N + c] = acc[i][j][r] + bv;
      }
    }
  }
}

// ---------------------------------------------------------------------------
extern "C" void kernel_launch(void* const* d_in, const int* in_sizes, int n_in,
                              void* d_out, int out_size, void* d_ws, size_t ws_size,
                              hipStream_t stream) {
  const float* x    = (const float*)d_in[0];
  const float* w    = (const float*)d_in[1];
  const float* bias = (const float*)d_in[2];
  float* out = (float*)d_out;

  const long long xn = in_sizes[0];   // M*K
  const long long wn = in_sizes[1];   // N*K
  const int N = in_sizes[2];
  const int K = (int)(wn / N);
  const int M = (int)(xn / K);

  unsigned short* xb = (unsigned short*)d_ws;
  unsigned short* wb = xb + (size_t)M * K;

  const int castBlocks  = (int)(xn / (256 * 8));    // 8 elems/thread
  const int quantBlocks = (int)(wn / (256 * 4));    // 1024 elems/block
  prep_kernel<<<castBlocks + quantBlocks, 256, 0, stream>>>(x, xb, w, wb,
                                                            castBlocks);
  gemm_bt_kernel<<<dim3(N / BN, M / BM), 256, 0, stream>>>(xb, wb, bias, out,
                                                           M, N, K);
}